// Round 5
// baseline (4237.031 us; speedup 1.0000x reference)
//
#include <hip/hip_runtime.h>
#include <math.h>

#define HIDDEN 512
#define WINDOW 24
#define KSZ 3
#define BATCH 2048
#define L_IN 514
#define H4 2048
#define LDT 40                    // padded LDS row stride (shorts) for 32-k tiles
#define BH (BATCH * HIDDEN)
#define NBLK 512                  // persistent scan kernel grid (2 blocks/CU)

typedef short short8 __attribute__((ext_vector_type(8)));
typedef float floatx4 __attribute__((ext_vector_type(4)));

__device__ __forceinline__ floatx4 mfma16(short8 a, short8 b, floatx4 c) {
    return __builtin_amdgcn_mfma_f32_16x16x32_bf16(a, b, c, 0, 0, 0);
}
__device__ __forceinline__ unsigned short f2bf(float x) {
    union { float f; unsigned u; } v; v.f = x;
    unsigned r = v.u + 0x7fff + ((v.u >> 16) & 1);   // RTNE
    return (unsigned short)(r >> 16);
}
__device__ __forceinline__ float bf2f(unsigned short u) {
    union { unsigned u; float f; } v; v.u = ((unsigned)u) << 16;
    return v.f;
}
__device__ __forceinline__ float sigmoidf(float x) { return 1.f / (1.f + expf(-x)); }

// Hand-rolled grid barrier (replaces cooperative grid.sync, which silently
// failed to launch). Each slot is single-use per kernel launch (zeroed by
// init_kernel). Agent-scope release/acquire + __threadfence publishes plain
// stores across non-coherent per-XCD L2s (G16).
__device__ __forceinline__ void grid_barrier(int* bar, int slot) {
    __syncthreads();
    if (threadIdx.x == 0) {
        __threadfence();   // publish prior writes (L2 writeback)
        __hip_atomic_fetch_add(&bar[slot], 1, __ATOMIC_RELEASE, __HIP_MEMORY_SCOPE_AGENT);
        while (__hip_atomic_load(&bar[slot], __ATOMIC_ACQUIRE, __HIP_MEMORY_SCOPE_AGENT)
               < NBLK) __builtin_amdgcn_s_sleep(2);
        __threadfence();   // invalidate stale L1/L2 before cross-block reads
    }
    __syncthreads();
}

// ---------------------------------------------------------------------------
// cvt5: fp32 -> bf16 for Wd, Ud, Whh, d_init, s_init (one kernel, float4-wide)
// ---------------------------------------------------------------------------
__global__ void cvt5_kernel(const float* __restrict__ s0, unsigned short* __restrict__ d0,
                            const float* __restrict__ s1, unsigned short* __restrict__ d1,
                            const float* __restrict__ s2, unsigned short* __restrict__ d2,
                            const float* __restrict__ s3, unsigned short* __restrict__ d3,
                            const float* __restrict__ s4, unsigned short* __restrict__ d4) {
    const int g = blockIdx.x * blockDim.x + threadIdx.x;   // one float4 per thread
    const float* src; unsigned short* dst; int off;
    if      (g < 131072) { src = s0; dst = d0; off = g; }
    else if (g < 196608) { src = s1; dst = d1; off = g - 131072; }
    else if (g < 458752) { src = s2; dst = d2; off = g - 196608; }
    else if (g < 720896) { src = s3; dst = d3; off = g - 458752; }
    else if (g < 983040) { src = s4; dst = d4; off = g - 720896; }
    else return;
    float4 v = ((const float4*)src)[off];
    uint2 u;
    u.x = (unsigned)f2bf(v.x) | ((unsigned)f2bf(v.y) << 16);
    u.y = (unsigned)f2bf(v.z) | ((unsigned)f2bf(v.w) << 16);
    ((uint2*)dst)[off] = u;
}

// ---------------------------------------------------------------------------
// conv1d(2->24, k=3, valid) + bias + relu -> Htb bf16 [t][b][i], 2-packed stores
// ---------------------------------------------------------------------------
__global__ void conv_kernel(const float* __restrict__ Z, const float* __restrict__ conv_w,
                            const float* __restrict__ conv_b,
                            unsigned int* __restrict__ Htu) {
    __shared__ float cw[WINDOW * 6];
    __shared__ float cb[WINDOW];
    const int b = blockIdx.x;
    if (threadIdx.x < WINDOW * 6) cw[threadIdx.x] = conv_w[threadIdx.x];
    if (threadIdx.x < WINDOW) cb[threadIdx.x] = conv_b[threadIdx.x];
    __syncthreads();
    const float* z0 = Z + (size_t)b * L_IN;
    const float* z1 = z0 + (size_t)BATCH * L_IN;
    const int i0 = threadIdx.x * 2;
    const float a0 = z0[i0], a1 = z0[i0 + 1], a2 = z0[i0 + 2], a3 = z0[i0 + 3];
    const float c0 = z1[i0], c1 = z1[i0 + 1], c2 = z1[i0 + 2], c3 = z1[i0 + 3];
#pragma unroll
    for (int o = 0; o < WINDOW; ++o) {
        const float* wc = cw + o * 6;
        float v0 = fmaxf(cb[o] + a0 * wc[0] + a1 * wc[1] + a2 * wc[2]
                               + c0 * wc[3] + c1 * wc[4] + c2 * wc[5], 0.f);
        float v1 = fmaxf(cb[o] + a1 * wc[0] + a2 * wc[1] + a3 * wc[2]
                               + c1 * wc[3] + c2 * wc[4] + c3 * wc[5], 0.f);
        Htu[((size_t)o * BATCH + b) * 256 + threadIdx.x] =
            (unsigned)f2bf(v0) | ((unsigned)f2bf(v1) << 16);
    }
}

// ---------------------------------------------------------------------------
// hw[t][b] = H_t[b,:] . w[24:]
// ---------------------------------------------------------------------------
__global__ void hw_kernel(const unsigned short* __restrict__ Htb,
                          const float* __restrict__ w, float* __restrict__ hw) {
    const int row = blockIdx.x * 4 + (threadIdx.x >> 6);   // 0 .. 24*2048-1
    const int lane = threadIdx.x & 63;
    short8 v = *(const short8*)(Htb + (size_t)row * HIDDEN + lane * 8);
    float acc = 0.f;
#pragma unroll
    for (int j = 0; j < 8; ++j)
        acc += bf2f((unsigned short)v[j]) * w[WINDOW + lane * 8 + j];
    for (int m = 32; m; m >>= 1) acc += __shfl_xor(acc, m, 64);
    if (lane == 0) hw[row] = acc;
}

// ---------------------------------------------------------------------------
// Gb = Htb[49152 x 512] @ Udb^T  (bf16 out).  64x64 tile, 4 waves, MFMA.
// XCD-clustered swizzle: the 8 N-tiles sharing an A-tile land on one XCD.
// ---------------------------------------------------------------------------
__global__ __launch_bounds__(256) void g_gemm_mfma(const unsigned short* __restrict__ Htb,
                                                   const unsigned short* __restrict__ Udb,
                                                   unsigned short* __restrict__ Gb) {
    __shared__ __align__(16) short As[64 * LDT];
    __shared__ __align__(16) short Bs[64 * LDT];
    const int blk = blockIdx.x;                 // 0..6143
    const int xcd = blk & 7;
    const int grp = blk >> 3;                   // 0..767
    const int nt  = grp & 7;                    // n-tile 0..7 (inner on one XCD)
    const int mt  = (grp >> 3) * 8 + xcd;       // m-tile 0..767
    const int tid = threadIdx.x;
    const int wave = tid >> 6, lane = tid & 63;
    const int wm = wave >> 1, wn = wave & 1;
    const int quad = lane >> 4, lr = lane & 15, qk = quad * 8;
    const int m0 = mt * 64, n0 = nt * 64;
    const int arow = tid >> 2, aseg = tid & 3;
    floatx4 acc[2][2] = {};
    for (int k0 = 0; k0 < HIDDEN; k0 += 32) {
        *(float4*)(As + arow * LDT + aseg * 8) =
            *(const float4*)(Htb + (size_t)(m0 + arow) * HIDDEN + k0 + aseg * 8);
        *(float4*)(Bs + arow * LDT + aseg * 8) =
            *(const float4*)(Udb + (size_t)(n0 + arow) * HIDDEN + k0 + aseg * 8);
        __syncthreads();
        short8 a0 = *(const short8*)(As + (wm * 32 + lr) * LDT + qk);
        short8 a1 = *(const short8*)(As + (wm * 32 + 16 + lr) * LDT + qk);
        short8 b0 = *(const short8*)(Bs + (wn * 32 + lr) * LDT + qk);
        short8 b1 = *(const short8*)(Bs + (wn * 32 + 16 + lr) * LDT + qk);
        acc[0][0] = mfma16(a0, b0, acc[0][0]);
        acc[0][1] = mfma16(a0, b1, acc[0][1]);
        acc[1][0] = mfma16(a1, b0, acc[1][0]);
        acc[1][1] = mfma16(a1, b1, acc[1][1]);
        __syncthreads();
    }
#pragma unroll
    for (int mf = 0; mf < 2; ++mf)
#pragma unroll
        for (int nf = 0; nf < 2; ++nf)
#pragma unroll
            for (int r = 0; r < 4; ++r) {
                const int m = m0 + wm * 32 + mf * 16 + quad * 4 + r;
                const int n = n0 + wn * 32 + nf * 16 + lr;
                Gb[(size_t)m * HIDDEN + n] = f2bf(acc[mf][nf][r]);
            }
}

// ---------------------------------------------------------------------------
// init: yr_dot[b] = y_real[b,:24] . w[:24]; zero softmax accs + barrier slots
// ---------------------------------------------------------------------------
__global__ void init_kernel(const float* __restrict__ y_real, const float* __restrict__ w,
                            float* __restrict__ yr_dot, float* __restrict__ Sacc,
                            int* __restrict__ flags) {
    const int tid = blockIdx.x * blockDim.x + threadIdx.x;
    if (tid < BATCH) {
        float s = 0.f;
#pragma unroll
        for (int j = 0; j < WINDOW; ++j) s += y_real[tid * WINDOW + j] * w[j];
        yr_dot[tid] = s;
    }
    if (tid < 2 * WINDOW) Sacc[tid] = 0.f;
    if (tid < 3 * WINDOW) flags[tid] = 0;   // 24 softmax flags + 48 barrier slots
}

// ---------------------------------------------------------------------------
// Persistent scan kernel (NORMAL launch): all 24 steps, 2 grid barriers/step.
// Per step:
//   phase A: l-partials (d- and s-passes merged into one k-loop)   -> lpart
//   grid_barrier
//   phase B: (1) wave0 reduces its 4 b's, atomicAdd Se/Seh + release flag
//            (2) gates GEMM k-loop (hides the flag barrier)
//            (3) acquire flag, ctw += Seh/Se (identical in every block)
//            (4) fused LSTM epilogue; s-state lives in fp32 REGISTERS
//   grid_barrier
// Softmax max-subtraction dropped: |l| <= sum|vd| = sqrt(512) = 22.6,
// exp() spans [1.5e-10, 6.6e9] — fp32-safe, ratio unchanged.
// ---------------------------------------------------------------------------
__global__ __launch_bounds__(256, 2) void scan_kernel(
        unsigned short* __restrict__ db0, unsigned short* __restrict__ db1,
        unsigned short* __restrict__ sb0, unsigned short* __restrict__ sb1,
        const unsigned short* __restrict__ Wdb, const unsigned short* __restrict__ Gb,
        const float* __restrict__ vd, float* __restrict__ lpart,
        const float* __restrict__ hw, const float* __restrict__ yr_dot,
        const unsigned short* __restrict__ Whhb, const float* __restrict__ Wih,
        const float* __restrict__ bih, const float* __restrict__ bhh,
        const float* __restrict__ b00, const float* __restrict__ s_init,
        float* __restrict__ Sacc, int* __restrict__ flags,
        float* __restrict__ y_out, float* __restrict__ d_out, float* __restrict__ s_out) {
    __shared__ __align__(16) short smA[2 * 64 * LDT];   // A: d-tile | s-tile ; B: As
    __shared__ __align__(16) short smB[4 * 32 * LDT];   // A: Bd | Bs ; B: 4 gate tiles
    __shared__ float red[2][64];
    __shared__ float sS[2];

    int* bar = flags + WINDOW;               // 48 single-use barrier slots

    const int tid = threadIdx.x;
    const int wave = tid >> 6, lane = tid & 63;
    const int wm = wave >> 1, wn = wave & 1;
    const int quad = lane >> 4, lr = lane & 15, qk = quad * 8;
    const int blk = blockIdx.x;
    const int m0 = (blk & 31) * 64;
    const int nb = blk >> 5;                 // 0..15
    const int n0 = nb * 32;
    const int arow = tid >> 2, aseg = tid & 3;
    const int i = n0 + wn * 16 + lr;

    // persistent per-thread state: this block owns the same (b,i) tile all steps
    float s_reg[2][4], yrv[2][4];
    float wi[4], cbv[4];
#pragma unroll
    for (int mf = 0; mf < 2; ++mf)
#pragma unroll
        for (int r = 0; r < 4; ++r) {
            const int b = m0 + wm * 32 + mf * 16 + quad * 4 + r;
            s_reg[mf][r] = s_init[(size_t)b * HIDDEN + i];
            yrv[mf][r] = yr_dot[b];
        }
#pragma unroll
    for (int g = 0; g < 4; ++g) {
        wi[g] = Wih[g * HIDDEN + i];
        cbv[g] = bih[g * HIDDEN + i] + bhh[g * HIDDEN + i];
    }
    const float b00v = b00[0];
    const float vdi = vd[i];
    float ctw = 0.f;

    short* Asd = smA;
    short* Ass = smA + 64 * LDT;
    short* Bsd = smB;
    short* Bss = smB + 32 * LDT;

    for (int t = 0; t < WINDOW; ++t) {
        const unsigned short* dcur = (t & 1) ? db1 : db0;
        const unsigned short* scur = (t & 1) ? sb1 : sb0;
        unsigned short* dnxt = (t & 1) ? db0 : db1;
        unsigned short* snxt = (t & 1) ? sb0 : sb1;
        const unsigned short* Gtb = Gb + (size_t)t * BH;

        // ---------------- phase A: l partials ----------------
        floatx4 accA[2] = {};
        for (int k0 = 0; k0 < HIDDEN; k0 += 32) {
            *(float4*)(Asd + arow * LDT + aseg * 8) =
                *(const float4*)(dcur + (size_t)(m0 + arow) * HIDDEN + k0 + aseg * 8);
            *(float4*)(Ass + arow * LDT + aseg * 8) =
                *(const float4*)(scur + (size_t)(m0 + arow) * HIDDEN + k0 + aseg * 8);
            {
                const int r2 = tid & 127, brow = r2 >> 2, bseg = r2 & 3;
                short* dst = (tid < 128) ? Bsd : Bss;
                const int coff = (tid < 128) ? 0 : HIDDEN;
                *(float4*)(dst + brow * LDT + bseg * 8) =
                    *(const float4*)(Wdb + (size_t)(n0 + brow) * (2 * HIDDEN) + coff + k0 + bseg * 8);
            }
            __syncthreads();
            short8 ad0 = *(const short8*)(Asd + (wm * 32 + lr) * LDT + qk);
            short8 ad1 = *(const short8*)(Asd + (wm * 32 + 16 + lr) * LDT + qk);
            short8 as0 = *(const short8*)(Ass + (wm * 32 + lr) * LDT + qk);
            short8 as1 = *(const short8*)(Ass + (wm * 32 + 16 + lr) * LDT + qk);
            short8 bd  = *(const short8*)(Bsd + (wn * 16 + lr) * LDT + qk);
            short8 bs  = *(const short8*)(Bss + (wn * 16 + lr) * LDT + qk);
            accA[0] = mfma16(ad0, bd, accA[0]);
            accA[1] = mfma16(ad1, bd, accA[1]);
            accA[0] = mfma16(as0, bs, accA[0]);
            accA[1] = mfma16(as1, bs, accA[1]);
            __syncthreads();
        }
#pragma unroll
        for (int mf = 0; mf < 2; ++mf) {
            float rs[4];
#pragma unroll
            for (int r = 0; r < 4; ++r) {
                const int b = m0 + wm * 32 + mf * 16 + quad * 4 + r;
                float v = tanhf(accA[mf][r] + bf2f(Gtb[(size_t)b * HIDDEN + i])) * vdi;
                for (int msk = 1; msk < 16; msk <<= 1) v += __shfl_xor(v, msk, 16);
                rs[r] = v;
            }
            if (lr == 0)
#pragma unroll
                for (int r = 0; r < 4; ++r)
                    red[wn][wm * 32 + mf * 16 + quad * 4 + r] = rs[r];
        }
        __syncthreads();
        if (tid < 64)
            __hip_atomic_store(&lpart[(size_t)nb * BATCH + m0 + tid],
                               red[0][tid] + red[1][tid],
                               __ATOMIC_RELAXED, __HIP_MEMORY_SCOPE_AGENT);

        grid_barrier(bar, 2 * t);

        // ---------------- phase B ----------------
        // B1: wave0 reduces this block's 4 batch rows into the softmax sums
        if (tid < 64) {
            const int p = tid & 15, j = tid >> 4;
            const int bb = blk * 4 + j;
            float val = __hip_atomic_load(&lpart[(size_t)p * BATCH + bb],
                                          __ATOMIC_RELAXED, __HIP_MEMORY_SCOPE_AGENT);
            for (int m = 1; m < 16; m <<= 1) val += __shfl_xor(val, m, 16);
            float e = expf(val);
            float eh = e * hw[(size_t)t * BATCH + bb];
            e  += __shfl_xor(e, 16, 64);  e  += __shfl_xor(e, 32, 64);
            eh += __shfl_xor(eh, 16, 64); eh += __shfl_xor(eh, 32, 64);
            if (tid == 0) {
                __hip_atomic_fetch_add(&Sacc[2 * t], e, __ATOMIC_RELAXED, __HIP_MEMORY_SCOPE_AGENT);
                __hip_atomic_fetch_add(&Sacc[2 * t + 1], eh, __ATOMIC_RELAXED, __HIP_MEMORY_SCOPE_AGENT);
                __hip_atomic_fetch_add(&flags[t], 1, __ATOMIC_RELEASE, __HIP_MEMORY_SCOPE_AGENT);
            }
        }

        // B2: gates GEMM (does not need ys; hides the flag barrier)
        floatx4 accG[4][2] = {};
        for (int k0 = 0; k0 < HIDDEN; k0 += 32) {
            *(float4*)(smA + arow * LDT + aseg * 8) =
                *(const float4*)(dcur + (size_t)(m0 + arow) * HIDDEN + k0 + aseg * 8);
#pragma unroll
            for (int j = 0; j < 2; ++j) {
                const int c = tid + 256 * j;         // 512 chunks: 4g x 32row x 4seg
                const int g = c >> 7, cc = c & 127, row = cc >> 2, seg = cc & 3;
                *(float4*)(smB + g * 32 * LDT + row * LDT + seg * 8) =
                    *(const float4*)(Whhb + (size_t)(g * HIDDEN + n0 + row) * HIDDEN + k0 + seg * 8);
            }
            __syncthreads();
            short8 a0 = *(const short8*)(smA + (wm * 32 + lr) * LDT + qk);
            short8 a1 = *(const short8*)(smA + (wm * 32 + 16 + lr) * LDT + qk);
#pragma unroll
            for (int g = 0; g < 4; ++g) {
                short8 bg = *(const short8*)(smB + g * 32 * LDT + (wn * 16 + lr) * LDT + qk);
                accG[g][0] = mfma16(a0, bg, accG[g][0]);
                accG[g][1] = mfma16(a1, bg, accG[g][1]);
            }
            __syncthreads();
        }

        // B3: acquire the softmax totals; ctw identical in every block
        if (tid == 0) {
            while (__hip_atomic_load(&flags[t], __ATOMIC_ACQUIRE, __HIP_MEMORY_SCOPE_AGENT)
                   < (int)NBLK) __builtin_amdgcn_s_sleep(2);
            sS[0] = __hip_atomic_load(&Sacc[2 * t], __ATOMIC_RELAXED, __HIP_MEMORY_SCOPE_AGENT);
            sS[1] = __hip_atomic_load(&Sacc[2 * t + 1], __ATOMIC_RELAXED, __HIP_MEMORY_SCOPE_AGENT);
        }
        __syncthreads();
        ctw += sS[1] / sS[0];
        const float ys = ctw + b00v;
        const bool last = (t == WINDOW - 1);

        // B4: fused LSTM epilogue, s-state in registers
#pragma unroll
    for (int mf = 0; mf < 2; ++mf)
#pragma unroll
            for (int r = 0; r < 4; ++r) {
                const int b = m0 + wm * 32 + mf * 16 + quad * 4 + r;
                const float yf = yrv[mf][r] + ys;
                const size_t idx = (size_t)b * HIDDEN + i;
                const float ig = accG[0][mf][r] + yf * wi[0] + cbv[0];
                const float fg = accG[1][mf][r] + yf * wi[1] + cbv[1];
                const float gg = accG[2][mf][r] + yf * wi[2] + cbv[2];
                const float og = accG[3][mf][r] + yf * wi[3] + cbv[3];
                const float sn = sigmoidf(fg) * s_reg[mf][r] + sigmoidf(ig) * tanhf(gg);
                const float dn = sigmoidf(og) * tanhf(sn);
                s_reg[mf][r] = sn;
                if (last) {
                    s_out[idx] = sn;
                    d_out[idx] = dn;
                    if (nb == 0 && wn == 0 && lr == 0) y_out[b] = yf;
                } else {
                    snxt[idx] = f2bf(sn);
                    dnxt[idx] = f2bf(dn);
                }
            }
        if (!last) grid_barrier(bar, 2 * t + 1);
    }
}

// ---------------------------------------------------------------------------
extern "C" void kernel_launch(void* const* d_in, const int* in_sizes, int n_in,
                              void* d_out, int out_size, void* d_ws, size_t ws_size,
                              hipStream_t stream) {
    const float* Z      = (const float*)d_in[0];
    const float* d_init = (const float*)d_in[1];
    const float* s_init = (const float*)d_in[2];
    const float* y_real = (const float*)d_in[3];
    const float* vd     = (const float*)d_in[4];
    const float* Wd     = (const float*)d_in[5];
    const float* Ud     = (const float*)d_in[6];
    const float* w      = (const float*)d_in[7];
    const float* b00    = (const float*)d_in[8];
    const float* conv_w = (const float*)d_in[9];
    const float* conv_b = (const float*)d_in[10];
    const float* Wih    = (const float*)d_in[11];
    const float* Whh    = (const float*)d_in[12];
    const float* bih    = (const float*)d_in[13];
    const float* bhh    = (const float*)d_in[14];

    float* ws = (float*)d_ws;
    size_t off = 0;
    unsigned short* Htb = (unsigned short*)(ws + off);  off += (size_t)WINDOW * BH / 2;
    unsigned short* Gb  = (unsigned short*)(ws + off);  off += (size_t)WINDOW * BH / 2;
    unsigned short* dbb0 = (unsigned short*)(ws + off);  off += BH / 2;
    unsigned short* dbb1 = (unsigned short*)(ws + off);  off += BH / 2;
    unsigned short* sbb0 = (unsigned short*)(ws + off);  off += BH / 2;
    unsigned short* sbb1 = (unsigned short*)(ws + off);  off += BH / 2;
    unsigned short* Wdb  = (unsigned short*)(ws + off);  off += (size_t)HIDDEN * 2 * HIDDEN / 2;
    unsigned short* Udb  = (unsigned short*)(ws + off);  off += (size_t)HIDDEN * HIDDEN / 2;
    unsigned short* Whhb = (unsigned short*)(ws + off);  off += (size_t)H4 * HIDDEN / 2;
    float* hw     = ws + off;  off += (size_t)WINDOW * BATCH;
    float* lpart  = ws + off;  off += (size_t)16 * BATCH;
    float* yr_dot = ws + off;  off += BATCH;
    float* Sacc   = ws + off;  off += 2 * WINDOW;
    int*   flags  = (int*)(ws + off);  off += 3 * WINDOW;  // 24 flags + 48 barrier slots

    float* out = (float*)d_out;
    float* y_out   = out;
    float* d_out_f = out + BATCH;
    float* s_out_f = out + BATCH + (size_t)BH;

    // --- one-time prep ---
    cvt5_kernel<<<3840, 256, 0, stream>>>(Wd, Wdb, Ud, Udb, Whh, Whhb,
                                          d_init, dbb0, s_init, sbb0);
    conv_kernel<<<BATCH, 256, 0, stream>>>(Z, conv_w, conv_b, (unsigned int*)Htb);
    hw_kernel<<<(WINDOW * BATCH) / 4, 256, 0, stream>>>(Htb, w, hw);
    g_gemm_mfma<<<768 * 8, 256, 0, stream>>>(Htb, Udb, Gb);
    init_kernel<<<8, 256, 0, stream>>>(y_real, w, yr_dot, Sacc, flags);

    // --- one persistent kernel for the whole 24-step scan (normal launch) ---
    scan_kernel<<<NBLK, 256, 0, stream>>>(
        dbb0, dbb1, sbb0, sbb1, Wdb, Gb, vd, lpart, hw, yr_dot,
        Whhb, Wih, bih, bhh, b00, s_init, Sacc, flags,
        y_out, d_out_f, s_out_f);
}

// Round 6
// 1230.878 us; speedup vs baseline: 3.4423x; 3.4423x over previous
//
#include <hip/hip_runtime.h>
#include <math.h>

#define HIDDEN 512
#define WINDOW 24
#define KSZ 3
#define BATCH 2048
#define L_IN 514
#define H4 2048
#define LDT 40                    // padded LDS row stride (shorts) for 32-k tiles
#define BH (BATCH * HIDDEN)

typedef short short8 __attribute__((ext_vector_type(8)));
typedef float floatx4 __attribute__((ext_vector_type(4)));

__device__ __forceinline__ floatx4 mfma16(short8 a, short8 b, floatx4 c) {
    return __builtin_amdgcn_mfma_f32_16x16x32_bf16(a, b, c, 0, 0, 0);
}
__device__ __forceinline__ unsigned short f2bf(float x) {
    union { float f; unsigned u; } v; v.f = x;
    unsigned r = v.u + 0x7fff + ((v.u >> 16) & 1);   // RTNE
    return (unsigned short)(r >> 16);
}
__device__ __forceinline__ float bf2f(unsigned short u) {
    union { unsigned u; float f; } v; v.u = ((unsigned)u) << 16;
    return v.f;
}
__device__ __forceinline__ float sigmoidf(float x) { return 1.f / (1.f + expf(-x)); }

// ---------------------------------------------------------------------------
// cvt5: fp32 -> bf16 for Wd, Ud, Whh, d_init, s_init.
// Whh is REPACKED gate-interleaved: src row (g*512+i) -> dst row
// (i>>4)*64 + g*16 + (i&15), so a 128-wide GEMM tile holds all 4 gates of
// each i, 16 columns apart (nf index == gate).
// ---------------------------------------------------------------------------
__global__ void cvt5_kernel(const float* __restrict__ s0, unsigned short* __restrict__ d0,
                            const float* __restrict__ s1, unsigned short* __restrict__ d1,
                            const float* __restrict__ s2, unsigned short* __restrict__ d2,
                            const float* __restrict__ s3, unsigned short* __restrict__ d3,
                            const float* __restrict__ s4, unsigned short* __restrict__ d4) {
    const int g = blockIdx.x * blockDim.x + threadIdx.x;   // one float4 per thread
    const float* src; unsigned short* dst; int off, offd;
    if      (g < 131072) { src = s0; dst = d0; off = g; offd = off; }
    else if (g < 196608) { src = s1; dst = d1; off = g - 131072; offd = off; }
    else if (g < 458752) {
        src = s2; dst = d2; off = g - 196608;
        const int row = off >> 7, seg = off & 127;       // 128 float4 per 512-col row
        const int gg = row >> 9, ii = row & 511;
        const int drow = ((ii >> 4) << 6) + (gg << 4) + (ii & 15);
        offd = drow * 128 + seg;
    }
    else if (g < 720896) { src = s3; dst = d3; off = g - 458752; offd = off; }
    else if (g < 983040) { src = s4; dst = d4; off = g - 720896; offd = off; }
    else return;
    float4 v = ((const float4*)src)[off];
    uint2 u;
    u.x = (unsigned)f2bf(v.x) | ((unsigned)f2bf(v.y) << 16);
    u.y = (unsigned)f2bf(v.z) | ((unsigned)f2bf(v.w) << 16);
    ((uint2*)dst)[offd] = u;
}

// ---------------------------------------------------------------------------
// conv1d(2->24, k=3, valid) + bias + relu -> Htb bf16 [t][b][i], 2-packed stores
// ---------------------------------------------------------------------------
__global__ void conv_kernel(const float* __restrict__ Z, const float* __restrict__ conv_w,
                            const float* __restrict__ conv_b,
                            unsigned int* __restrict__ Htu) {
    __shared__ float cw[WINDOW * 6];
    __shared__ float cb[WINDOW];
    const int b = blockIdx.x;
    if (threadIdx.x < WINDOW * 6) cw[threadIdx.x] = conv_w[threadIdx.x];
    if (threadIdx.x < WINDOW) cb[threadIdx.x] = conv_b[threadIdx.x];
    __syncthreads();
    const float* z0 = Z + (size_t)b * L_IN;
    const float* z1 = z0 + (size_t)BATCH * L_IN;
    const int i0 = threadIdx.x * 2;
    const float a0 = z0[i0], a1 = z0[i0 + 1], a2 = z0[i0 + 2], a3 = z0[i0 + 3];
    const float c0 = z1[i0], c1 = z1[i0 + 1], c2 = z1[i0 + 2], c3 = z1[i0 + 3];
#pragma unroll
    for (int o = 0; o < WINDOW; ++o) {
        const float* wc = cw + o * 6;
        float v0 = fmaxf(cb[o] + a0 * wc[0] + a1 * wc[1] + a2 * wc[2]
                               + c0 * wc[3] + c1 * wc[4] + c2 * wc[5], 0.f);
        float v1 = fmaxf(cb[o] + a1 * wc[0] + a2 * wc[1] + a3 * wc[2]
                               + c1 * wc[3] + c2 * wc[4] + c3 * wc[5], 0.f);
        Htu[((size_t)o * BATCH + b) * 256 + threadIdx.x] =
            (unsigned)f2bf(v0) | ((unsigned)f2bf(v1) << 16);
    }
}

// ---------------------------------------------------------------------------
// hw[t][b] = H_t[b,:] . w[24:]
// ---------------------------------------------------------------------------
__global__ void hw_kernel(const unsigned short* __restrict__ Htb,
                          const float* __restrict__ w, float* __restrict__ hw) {
    const int row = blockIdx.x * 4 + (threadIdx.x >> 6);   // 0 .. 24*2048-1
    const int lane = threadIdx.x & 63;
    short8 v = *(const short8*)(Htb + (size_t)row * HIDDEN + lane * 8);
    float acc = 0.f;
#pragma unroll
    for (int j = 0; j < 8; ++j)
        acc += bf2f((unsigned short)v[j]) * w[WINDOW + lane * 8 + j];
    for (int m = 32; m; m >>= 1) acc += __shfl_xor(acc, m, 64);
    if (lane == 0) hw[row] = acc;
}

// ---------------------------------------------------------------------------
// Gb = Htb[49152 x 512] @ Udb^T  (bf16 out).  64x64 tile, 4 waves, MFMA.
// XCD-clustered swizzle: the 8 N-tiles sharing an A-tile land on one XCD.
// ---------------------------------------------------------------------------
__global__ __launch_bounds__(256) void g_gemm_mfma(const unsigned short* __restrict__ Htb,
                                                   const unsigned short* __restrict__ Udb,
                                                   unsigned short* __restrict__ Gb) {
    __shared__ __align__(16) short As[64 * LDT];
    __shared__ __align__(16) short Bs[64 * LDT];
    const int blk = blockIdx.x;                 // 0..6143
    const int xcd = blk & 7;
    const int grp = blk >> 3;                   // 0..767
    const int nt  = grp & 7;                    // n-tile 0..7 (inner on one XCD)
    const int mt  = (grp >> 3) * 8 + xcd;       // m-tile 0..767
    const int tid = threadIdx.x;
    const int wave = tid >> 6, lane = tid & 63;
    const int wm = wave >> 1, wn = wave & 1;
    const int quad = lane >> 4, lr = lane & 15, qk = quad * 8;
    const int m0 = mt * 64, n0 = nt * 64;
    const int arow = tid >> 2, aseg = tid & 3;
    floatx4 acc[2][2] = {};
    for (int k0 = 0; k0 < HIDDEN; k0 += 32) {
        *(float4*)(As + arow * LDT + aseg * 8) =
            *(const float4*)(Htb + (size_t)(m0 + arow) * HIDDEN + k0 + aseg * 8);
        *(float4*)(Bs + arow * LDT + aseg * 8) =
            *(const float4*)(Udb + (size_t)(n0 + arow) * HIDDEN + k0 + aseg * 8);
        __syncthreads();
        short8 a0 = *(const short8*)(As + (wm * 32 + lr) * LDT + qk);
        short8 a1 = *(const short8*)(As + (wm * 32 + 16 + lr) * LDT + qk);
        short8 b0 = *(const short8*)(Bs + (wn * 32 + lr) * LDT + qk);
        short8 b1 = *(const short8*)(Bs + (wn * 32 + 16 + lr) * LDT + qk);
        acc[0][0] = mfma16(a0, b0, acc[0][0]);
        acc[0][1] = mfma16(a0, b1, acc[0][1]);
        acc[1][0] = mfma16(a1, b0, acc[1][0]);
        acc[1][1] = mfma16(a1, b1, acc[1][1]);
        __syncthreads();
    }
#pragma unroll
    for (int mf = 0; mf < 2; ++mf)
#pragma unroll
        for (int nf = 0; nf < 2; ++nf)
#pragma unroll
            for (int r = 0; r < 4; ++r) {
                const int m = m0 + wm * 32 + mf * 16 + quad * 4 + r;
                const int n = n0 + wn * 32 + nf * 16 + lr;
                Gb[(size_t)m * HIDDEN + n] = f2bf(acc[mf][nf][r]);
            }
}

// ---------------------------------------------------------------------------
// init: yr_dot[b] = y_real[b,:24] . w[:24]; zero Sacc/flags; ctwA[0]=0
// ---------------------------------------------------------------------------
__global__ void init_kernel(const float* __restrict__ y_real, const float* __restrict__ w,
                            float* __restrict__ yr_dot, float* __restrict__ Sacc,
                            int* __restrict__ flags, float* __restrict__ ctwA) {
    const int tid = blockIdx.x * blockDim.x + threadIdx.x;
    if (tid < BATCH) {
        float s = 0.f;
#pragma unroll
        for (int j = 0; j < WINDOW; ++j) s += y_real[tid * WINDOW + j] * w[j];
        yr_dot[tid] = s;
    }
    if (tid < 2 * WINDOW) Sacc[tid] = 0.f;
    if (tid < WINDOW) flags[tid] = 0;
    if (tid == 0) ctwA[0] = 0.f;
}

// ---------------------------------------------------------------------------
// S1 (VERBATIM from the proven 1286us baseline):
// lpart[nb][b] = sum_{i in nb-slice} tanh(d@WdA^T + s@WdB^T + G_t)*vd
// ---------------------------------------------------------------------------
__global__ __launch_bounds__(256) void s1_mfma(const unsigned short* __restrict__ db,
                                               const unsigned short* __restrict__ sb,
                                               const unsigned short* __restrict__ Wdb,
                                               const unsigned short* __restrict__ Gtb,
                                               const float* __restrict__ vd,
                                               float* __restrict__ lpart) {
    __shared__ __align__(16) short As[64 * LDT];
    __shared__ __align__(16) short Bs[32 * LDT];
    __shared__ float red[2][64];
    const int tid = threadIdx.x;
    const int wave = tid >> 6, lane = tid & 63;
    const int wm = wave >> 1, wn = wave & 1;
    const int quad = lane >> 4, lr = lane & 15, qk = quad * 8;
    const int m0 = (blockIdx.x & 31) * 64;
    const int nb = blockIdx.x >> 5;          // 0..15
    const int n0 = nb * 32;
    const int arow = tid >> 2, aseg = tid & 3;
    floatx4 acc[2] = {};
#pragma unroll
    for (int pass = 0; pass < 2; ++pass) {
        const unsigned short* A = pass ? sb : db;
        const unsigned short* B = Wdb + pass * HIDDEN;   // col offset in [512][1024]
        for (int k0 = 0; k0 < HIDDEN; k0 += 32) {
            *(float4*)(As + arow * LDT + aseg * 8) =
                *(const float4*)(A + (size_t)(m0 + arow) * HIDDEN + k0 + aseg * 8);
            if (tid < 128)
                *(float4*)(Bs + arow * LDT + aseg * 8) =
                    *(const float4*)(B + (size_t)(n0 + arow) * (2 * HIDDEN) + k0 + aseg * 8);
            __syncthreads();
            short8 a0 = *(const short8*)(As + (wm * 32 + lr) * LDT + qk);
            short8 a1 = *(const short8*)(As + (wm * 32 + 16 + lr) * LDT + qk);
            short8 b  = *(const short8*)(Bs + (wn * 16 + lr) * LDT + qk);
            acc[0] = mfma16(a0, b, acc[0]);
            acc[1] = mfma16(a1, b, acc[1]);
            __syncthreads();
        }
    }
#pragma unroll
    for (int mf = 0; mf < 2; ++mf) {
        float rs[4];
#pragma unroll
        for (int r = 0; r < 4; ++r) {
            const int b = m0 + wm * 32 + mf * 16 + quad * 4 + r;
            const int i = n0 + wn * 16 + lr;
            float v = tanhf(acc[mf][r] + bf2f(Gtb[(size_t)b * HIDDEN + i])) * vd[i];
            for (int msk = 1; msk < 16; msk <<= 1) v += __shfl_xor(v, msk, 16);
            rs[r] = v;
        }
        if (lr == 0)
#pragma unroll
            for (int r = 0; r < 4; ++r)
                red[wn][wm * 32 + mf * 16 + quad * 4 + r] = rs[r];
    }
    __syncthreads();
    if (tid < 64)
        lpart[(size_t)nb * BATCH + m0 + tid] = red[0][tid] + red[1][tid];
}

// ---------------------------------------------------------------------------
// gates+mid+LSTM: 128x128 tile (m93 geometry), 256 blocks, gate-interleaved
// Whhb. nt==0 blocks fold the softmax (mid) at kernel start via validated
// agent-atomics; all blocks spin-acquire after their GEMM (hidden latency).
// ---------------------------------------------------------------------------
__global__ __launch_bounds__(256) void gates_lstm_mfma(
        const unsigned short* __restrict__ db, const unsigned short* __restrict__ Whhb,
        const float* __restrict__ Wih, const float* __restrict__ bih,
        const float* __restrict__ bhh, const float* __restrict__ yr_dot,
        const float* __restrict__ lpart, const float* __restrict__ hw_t,
        float* __restrict__ Sacc, int* __restrict__ flags,
        float* __restrict__ ctwA, const float* __restrict__ b00,
        const float* __restrict__ s_old, float* __restrict__ s_new,
        float* __restrict__ d_new,
        unsigned short* __restrict__ sb_new, unsigned short* __restrict__ db_new,
        float* __restrict__ y_out, int t) {
    __shared__ __align__(16) short As[128 * LDT];
    __shared__ __align__(16) short Bs[128 * LDT];
    __shared__ float sSe[2];
    const int tid = threadIdx.x;
    const int wave = tid >> 6, lane = tid & 63;
    const int wm = wave >> 1, wn = wave & 1;
    const int quad = lane >> 4, lr = lane & 15, qk = quad * 8;
    const int mt = blockIdx.x & 15, nt = blockIdx.x >> 4;
    const int m0 = mt * 128, n0 = nt * 128;

    // --- mid fold: nt==0 blocks reduce their 128 b-rows of lpart ---
    if (nt == 0 && tid < 128) {
        const int b = m0 + tid;
        float l = 0.f;
#pragma unroll
        for (int p = 0; p < 16; ++p) l += lpart[(size_t)p * BATCH + b];
        float e = expf(l);
        float eh = e * hw_t[b];
#pragma unroll
        for (int m = 1; m < 64; m <<= 1) {
            e  += __shfl_xor(e, m, 64);
            eh += __shfl_xor(eh, m, 64);
        }
        if (lane == 0) {
            __hip_atomic_fetch_add(&Sacc[2 * t], e, __ATOMIC_RELAXED, __HIP_MEMORY_SCOPE_AGENT);
            __hip_atomic_fetch_add(&Sacc[2 * t + 1], eh, __ATOMIC_RELAXED, __HIP_MEMORY_SCOPE_AGENT);
        }
    }
    __syncthreads();   // drains the atomic adds of waves 0/1 (vmcnt before barrier)
    if (nt == 0 && tid == 0)
        __hip_atomic_fetch_add(&flags[t], 1, __ATOMIC_RELEASE, __HIP_MEMORY_SCOPE_AGENT);

    // --- gates GEMM: C[128 b][128 n], n = gate-interleaved i ---
    floatx4 acc[4][4] = {};   // [mf][g]
    for (int k0 = 0; k0 < HIDDEN; k0 += 32) {
#pragma unroll
        for (int j = 0; j < 2; ++j) {
            const int c = tid + 256 * j;          // 512 chunks: 128 rows x 4 segs
            const int row = c >> 2, seg = c & 3;
            *(float4*)(As + row * LDT + seg * 8) =
                *(const float4*)(db + (size_t)(m0 + row) * HIDDEN + k0 + seg * 8);
            *(float4*)(Bs + row * LDT + seg * 8) =
                *(const float4*)(Whhb + (size_t)(n0 + row) * HIDDEN + k0 + seg * 8);
        }
        __syncthreads();
        short8 a[4], bv[4];
#pragma unroll
        for (int f = 0; f < 4; ++f) {
            a[f]  = *(const short8*)(As + (wm * 64 + f * 16 + lr) * LDT + qk);
            bv[f] = *(const short8*)(Bs + (wn * 64 + f * 16 + lr) * LDT + qk);
        }
#pragma unroll
        for (int mf = 0; mf < 4; ++mf)
#pragma unroll
            for (int nf = 0; nf < 4; ++nf)
                acc[mf][nf] = mfma16(a[mf], bv[nf], acc[mf][nf]);
        __syncthreads();
    }

    // --- acquire softmax totals (GEMM hid the wait) ---
    if (tid == 0) {
        while (__hip_atomic_load(&flags[t], __ATOMIC_ACQUIRE, __HIP_MEMORY_SCOPE_AGENT) < 16)
            __builtin_amdgcn_s_sleep(2);
        sSe[0] = __hip_atomic_load(&Sacc[2 * t], __ATOMIC_RELAXED, __HIP_MEMORY_SCOPE_AGENT);
        sSe[1] = __hip_atomic_load(&Sacc[2 * t + 1], __ATOMIC_RELAXED, __HIP_MEMORY_SCOPE_AGENT);
    }
    __syncthreads();
    const float ctw = ctwA[t] + sSe[1] / sSe[0];
    const float ys = ctw + b00[0];
    if (blockIdx.x == 0 && tid == 0) ctwA[t + 1] = ctw;   // next launch reads (plain)
    if (y_out != nullptr && nt == 0 && tid < 128)
        y_out[m0 + tid] = yr_dot[m0 + tid] + ys;

    // --- fused LSTM epilogue: thread owns one i, all 4 gates (nf==g) ---
    const int i = ((n0 + wn * 64) >> 2) + lr;
    float wi[4], cbv[4];
#pragma unroll
    for (int g = 0; g < 4; ++g) {
        wi[g] = Wih[g * HIDDEN + i];
        cbv[g] = bih[g * HIDDEN + i] + bhh[g * HIDDEN + i];
    }
#pragma unroll
    for (int mf = 0; mf < 4; ++mf)
#pragma unroll
        for (int r = 0; r < 4; ++r) {
            const int b = m0 + wm * 64 + mf * 16 + quad * 4 + r;
            const float yf = yr_dot[b] + ys;
            const size_t idx = (size_t)b * HIDDEN + i;
            const float ig = acc[mf][0][r] + yf * wi[0] + cbv[0];
            const float fg = acc[mf][1][r] + yf * wi[1] + cbv[1];
            const float gg = acc[mf][2][r] + yf * wi[2] + cbv[2];
            const float og = acc[mf][3][r] + yf * wi[3] + cbv[3];
            const float sn = sigmoidf(fg) * s_old[idx] + sigmoidf(ig) * tanhf(gg);
            const float dn = sigmoidf(og) * tanhf(sn);
            s_new[idx] = sn;
            sb_new[idx] = f2bf(sn);
            db_new[idx] = f2bf(dn);
            if (d_new != nullptr) d_new[idx] = dn;
        }
}

// ---------------------------------------------------------------------------
extern "C" void kernel_launch(void* const* d_in, const int* in_sizes, int n_in,
                              void* d_out, int out_size, void* d_ws, size_t ws_size,
                              hipStream_t stream) {
    const float* Z      = (const float*)d_in[0];
    const float* d_init = (const float*)d_in[1];
    const float* s_init = (const float*)d_in[2];
    const float* y_real = (const float*)d_in[3];
    const float* vd     = (const float*)d_in[4];
    const float* Wd     = (const float*)d_in[5];
    const float* Ud     = (const float*)d_in[6];
    const float* w      = (const float*)d_in[7];
    const float* b00    = (const float*)d_in[8];
    const float* conv_w = (const float*)d_in[9];
    const float* conv_b = (const float*)d_in[10];
    const float* Wih    = (const float*)d_in[11];
    const float* Whh    = (const float*)d_in[12];
    const float* bih    = (const float*)d_in[13];
    const float* bhh    = (const float*)d_in[14];

    float* ws = (float*)d_ws;
    size_t off = 0;
    unsigned short* Htb = (unsigned short*)(ws + off);  off += (size_t)WINDOW * BH / 2;
    unsigned short* Gb  = (unsigned short*)(ws + off);  off += (size_t)WINDOW * BH / 2;
    unsigned short* dbb[2];
    dbb[0] = (unsigned short*)(ws + off);  off += BH / 2;
    dbb[1] = (unsigned short*)(ws + off);  off += BH / 2;
    unsigned short* sbb[2];
    sbb[0] = (unsigned short*)(ws + off);  off += BH / 2;
    sbb[1] = (unsigned short*)(ws + off);  off += BH / 2;
    float* sbuf[2];
    sbuf[0] = ws + off;  off += BH;
    sbuf[1] = ws + off;  off += BH;
    unsigned short* Wdb  = (unsigned short*)(ws + off);  off += (size_t)HIDDEN * 2 * HIDDEN / 2;
    unsigned short* Udb  = (unsigned short*)(ws + off);  off += (size_t)HIDDEN * HIDDEN / 2;
    unsigned short* Whhb = (unsigned short*)(ws + off);  off += (size_t)H4 * HIDDEN / 2;
    float* hw     = ws + off;  off += (size_t)WINDOW * BATCH;
    float* lpart  = ws + off;  off += (size_t)16 * BATCH;
    float* yr_dot = ws + off;  off += BATCH;
    float* Sacc   = ws + off;  off += 2 * WINDOW;
    float* ctwA   = ws + off;  off += WINDOW + 4;
    int*   flags  = (int*)(ws + off);  off += WINDOW;

    float* out = (float*)d_out;
    float* y_out   = out;
    float* d_out_f = out + BATCH;
    float* s_out_f = out + BATCH + (size_t)BH;

    // --- one-time prep ---
    cvt5_kernel<<<3840, 256, 0, stream>>>(Wd, Wdb, Ud, Udb, Whh, Whhb,
                                          d_init, dbb[0], s_init, sbb[0]);
    conv_kernel<<<BATCH, 256, 0, stream>>>(Z, conv_w, conv_b, (unsigned int*)Htb);
    hw_kernel<<<(WINDOW * BATCH) / 4, 256, 0, stream>>>(Htb, w, hw);
    g_gemm_mfma<<<768 * 8, 256, 0, stream>>>(Htb, Udb, Gb);
    init_kernel<<<8, 256, 0, stream>>>(y_real, w, yr_dot, Sacc, flags, ctwA);

    // --- scan over 24 steps: 2 launches/step ---
    const float* s_read = s_init;
    int pp = 0;
    for (int t = 0; t < WINDOW; ++t) {
        const unsigned short* Gtb = Gb + (size_t)t * BH;
        s1_mfma<<<512, 256, 0, stream>>>(dbb[pp], sbb[pp], Wdb, Gtb, vd, lpart);
        const bool last = (t == WINDOW - 1);
        float* s_w = last ? s_out_f : sbuf[t & 1];
        float* d_w = last ? d_out_f : nullptr;
        float* y_w = last ? y_out : nullptr;
        gates_lstm_mfma<<<256, 256, 0, stream>>>(dbb[pp], Whhb, Wih, bih, bhh, yr_dot,
                                                 lpart, hw + t * BATCH, Sacc, flags,
                                                 ctwA, b00, s_read, s_w, d_w,
                                                 sbb[1 - pp], dbb[1 - pp], y_w, t);
        s_read = s_w;
        pp ^= 1;
    }
}